// Round 5
// baseline (760.748 us; speedup 1.0000x reference)
//
#include <hip/hip_runtime.h>
#include <hip/hip_bf16.h>
#include <math.h>
#include <stdint.h>

#define TPB 256
#define NCB 32   // clusters per agg block

typedef __attribute__((ext_vector_type(8))) short bf16x8;
typedef __attribute__((ext_vector_type(4))) float f32x4;

__device__ __forceinline__ unsigned short f2bf(float f) {
    __hip_bfloat16 b = __float2bfloat16(f);
    return *(unsigned short*)&b;
}
__device__ __forceinline__ unsigned int pk2(float a, float b) {
    return (unsigned int)f2bf(a) | ((unsigned int)f2bf(b) << 16);
}
__device__ __forceinline__ bf16x8 zfrag() {
    bf16x8 z;
#pragma unroll
    for (int j = 0; j < 8; j++) z[j] = 0;
    return z;
}

// B-operand fragment for mfma_f32_16x16x32_bf16: B[k][n], n=lane&15,
// k=(lane>>4)*8+j. W is row-major [keff x dout]; zero-pad k>=keff.
__device__ __forceinline__ bf16x8 load_bfrag(const float* W, int dout,
                                             int keff, int ntile, int lane) {
    int nn = ntile * 16 + (lane & 15);
    int kq = (lane >> 4) * 8;
    bf16x8 f;
#pragma unroll
    for (int j = 0; j < 8; j++) {
        int k = kq + j;
        float w = (k < keff) ? W[k * dout + nn] : 0.f;
        f[j] = (short)f2bf(w);
    }
    return f;
}

// ---------------------------------------------------------------------------
// Sort stage 1: histogram of labels
// ---------------------------------------------------------------------------
__global__ __launch_bounds__(TPB) void hist_kernel(
    const int* __restrict__ labels, int* __restrict__ counts, int n)
{
    int i = blockIdx.x * TPB + threadIdx.x;
    if (i < n) atomicAdd(&counts[labels[i]], 1);
}

// ---------------------------------------------------------------------------
// Sort stage 2: exclusive prefix sum over C bins (single block, 1024 thr)
// ---------------------------------------------------------------------------
__global__ __launch_bounds__(1024) void scan_kernel(
    const int* __restrict__ counts, int* __restrict__ off,
    int* __restrict__ cursor, int C)
{
    __shared__ int part[1024];
    int t = threadIdx.x;
    int per = C / 1024;
    int b0 = t * per;
    int s = 0;
    for (int k = 0; k < per; k++) s += counts[b0 + k];
    part[t] = s;
    __syncthreads();
    for (int d = 1; d < 1024; d <<= 1) {
        int v = 0;
        if (t >= d) v = part[t - d];
        __syncthreads();
        if (t >= d) part[t] += v;
        __syncthreads();
    }
    int run = part[t] - s;
    for (int k = 0; k < per; k++) {
        off[b0 + k] = run;
        cursor[b0 + k] = run;
        run += counts[b0 + k];
    }
    if (t == 1023) off[C] = run;
}

// ---------------------------------------------------------------------------
// Stage 1: per-point MLP with MFMA on the fat layers.
// Wave batch = 64 points. L0/L1 in VALU (lane owns point); L2/L3/attn0 via
// mfma_f32_16x16x32_bf16 on 16-point subtiles (LDS transposes, per-wave).
// Output rows stored at atomically-claimed sorted slots (128B rows).
// ---------------------------------------------------------------------------
__global__ __launch_bounds__(TPB) void point_mlp_mfma(
    const float* __restrict__ pf, const int* __restrict__ labels,
    const float* __restrict__ centers, const float* __restrict__ points,
    const float* __restrict__ we0, const float* __restrict__ be0,
    const float* __restrict__ we1, const float* __restrict__ be1,
    const float* __restrict__ we2, const float* __restrict__ be2,
    const float* __restrict__ we3, const float* __restrict__ be3,
    const float* __restrict__ wa0, const float* __restrict__ ba0,
    const float* __restrict__ wa1, const float* __restrict__ ba1,
    int* __restrict__ cursor, unsigned short* __restrict__ tsort, int n)
{
    // per-wave LDS: xbuf[64][16] | h2buf[64][16] | h3buf[16][32] | tst[16][64]
    __shared__ unsigned short s_lds[4][3584];   // 7 KB per wave, 28 KB total
    int lane = threadIdx.x & 63;
    int wid  = threadIdx.x >> 6;
    int m    = lane & 15;
    int quad = lane >> 4;

    unsigned short* xbuf  = &s_lds[wid][0];
    unsigned short* h2buf = xbuf + 1024;
    unsigned short* h3buf = h2buf + 1024;
    unsigned short* tst   = h3buf + 512;

    // persistent weight fragments (loaded once per wave)
    bf16x8 bw2[2], bw3[4], bwa[4];
#pragma unroll
    for (int t = 0; t < 2; t++) bw2[t] = load_bfrag(we2, 32, 16, t, lane);
#pragma unroll
    for (int t = 0; t < 4; t++) bw3[t] = load_bfrag(we3, 64, 32, t, lane);
#pragma unroll
    for (int t = 0; t < 4; t++) bwa[t] = load_bfrag(wa0, 64, 11, t, lane);
    float bias2[2], bias3[4], biasa[4], wa1v[4];
#pragma unroll
    for (int t = 0; t < 2; t++) bias2[t] = be2[t * 16 + m];
#pragma unroll
    for (int t = 0; t < 4; t++) bias3[t] = be3[t * 16 + m];
#pragma unroll
    for (int t = 0; t < 4; t++) biasa[t] = ba0[t * 16 + m];
#pragma unroll
    for (int t = 0; t < 4; t++) wa1v[t]  = wa1[t * 16 + m];
    float ba1v = ba1[0];

    int gw = blockIdx.x * 4 + wid;
    int nw = gridDim.x * 4;

    for (int base = gw * 64; base < n; base += nw * 64) {
        int i = base + lane;
        bool valid = i < n;

        // ---- per-lane input build ----
        float x[11];
        if (valid) {
            const float4* pf4 = (const float4*)pf;
            float4 p0 = pf4[(size_t)i * 2 + 0];
            float4 p1 = pf4[(size_t)i * 2 + 1];
            x[0] = p0.x; x[1] = p0.y; x[2] = p0.z; x[3] = p0.w;
            x[4] = p1.x; x[5] = p1.y; x[6] = p1.z; x[7] = p1.w;
            int lbl = labels[i];
            x[8]  = centers[lbl * 3 + 0] - points[(size_t)i * 3 + 0];
            x[9]  = centers[lbl * 3 + 1] - points[(size_t)i * 3 + 1];
            x[10] = centers[lbl * 3 + 2] - points[(size_t)i * 3 + 2];
        } else {
#pragma unroll
            for (int k = 0; k < 11; k++) x[k] = 0.f;
        }
        int pos = 0;
        if (valid) pos = atomicAdd(&cursor[labels[i]], 1);

        // xbuf row (bf16, cols 11..15 zero)
        {
            uint4 lo = make_uint4(pk2(x[0], x[1]), pk2(x[2], x[3]),
                                  pk2(x[4], x[5]), pk2(x[6], x[7]));
            uint4 hi = make_uint4(pk2(x[8], x[9]), pk2(x[10], 0.f), 0u, 0u);
            *(uint4*)&xbuf[lane * 16 + 0] = lo;
            *(uint4*)&xbuf[lane * 16 + 8] = hi;
        }

        // ---- L0: 11->8, L1: 8->16 (VALU, lane owns point) ----
        float h1[8];
#pragma unroll
        for (int j = 0; j < 8; j++) {
            float v = be0[j];
#pragma unroll
            for (int k = 0; k < 11; k++) v = fmaf(x[k], we0[k * 8 + j], v);
            h1[j] = fmaxf(v, 0.f);
        }
        float h2[16];
#pragma unroll
        for (int j = 0; j < 16; j++) {
            float v = be1[j];
#pragma unroll
            for (int k = 0; k < 8; k++) v = fmaf(h1[k], we1[k * 16 + j], v);
            h2[j] = fmaxf(v, 0.f);
        }
        {
            uint4 lo = make_uint4(pk2(h2[0], h2[1]),  pk2(h2[2], h2[3]),
                                  pk2(h2[4], h2[5]),  pk2(h2[6], h2[7]));
            uint4 hi = make_uint4(pk2(h2[8], h2[9]),  pk2(h2[10], h2[11]),
                                  pk2(h2[12], h2[13]), pk2(h2[14], h2[15]));
            *(uint4*)&h2buf[lane * 16 + 0] = lo;
            *(uint4*)&h2buf[lane * 16 + 8] = hi;
        }

        // ---- per 16-point subtile: MFMA chain ----
#pragma unroll 1
        for (int s = 0; s < 4; s++) {
            // A-frags for L2 (h2, K=16) and attn0 (x, K=11): quads 2,3 zero
            bf16x8 a_h2 = zfrag(), a_x = zfrag();
            if (quad < 2) {
                a_h2 = *(bf16x8*)&h2buf[(s * 16 + m) * 16 + quad * 8];
                a_x  = *(bf16x8*)&xbuf [(s * 16 + m) * 16 + quad * 8];
            }

            // L2: 16->32 (2 ntiles)
            f32x4 acc2[2];
#pragma unroll
            for (int t = 0; t < 2; t++) {
                f32x4 c = {bias2[t], bias2[t], bias2[t], bias2[t]};
                acc2[t] = __builtin_amdgcn_mfma_f32_16x16x32_bf16(a_h2, bw2[t], c, 0, 0, 0);
            }
            // relu -> h3buf[16][32] (row=quad*4+r, col=t*16+m)
#pragma unroll
            for (int t = 0; t < 2; t++)
#pragma unroll
                for (int r = 0; r < 4; r++)
                    h3buf[(quad * 4 + r) * 32 + t * 16 + m] =
                        f2bf(fmaxf(acc2[t][r], 0.f));

            // L3 A-frag: row m, k=quad*8..+7 (K=32, all quads)
            bf16x8 a_h3 = *(bf16x8*)&h3buf[m * 32 + quad * 8];

            // L3: 32->64 (4 ntiles) and attn0: 11->64 (4 ntiles)
            f32x4 acc3[4], acca[4];
#pragma unroll
            for (int t = 0; t < 4; t++) {
                f32x4 c3 = {bias3[t], bias3[t], bias3[t], bias3[t]};
                acc3[t] = __builtin_amdgcn_mfma_f32_16x16x32_bf16(a_h3, bw3[t], c3, 0, 0, 0);
                f32x4 ca = {biasa[t], biasa[t], biasa[t], biasa[t]};
                acca[t] = __builtin_amdgcn_mfma_f32_16x16x32_bf16(a_x, bwa[t], ca, 0, 0, 0);
            }

            // attn1: s[p] = ba1 + sum_j relu(a[p][j]) * wa1[j]; 16-lane reduce
            float gate[4];
#pragma unroll
            for (int r = 0; r < 4; r++) {
                float pr = 0.f;
#pragma unroll
                for (int t = 0; t < 4; t++)
                    pr = fmaf(fmaxf(acca[t][r], 0.f), wa1v[t], pr);
                pr += __shfl_xor(pr, 1, 64);
                pr += __shfl_xor(pr, 2, 64);
                pr += __shfl_xor(pr, 4, 64);
                pr += __shfl_xor(pr, 8, 64);
                pr += ba1v;
                gate[r] = 1.f / (1.f + __expf(-pr));
            }

            // gated output -> tst[16][64]
#pragma unroll
            for (int t = 0; t < 4; t++)
#pragma unroll
                for (int r = 0; r < 4; r++)
                    tst[(quad * 4 + r) * 64 + t * 16 + m] =
                        f2bf(fmaxf(acc3[t][r], 0.f) * gate[r]);

            // store 16 rows (128B each) to sorted slots: 2 passes of 64x16B
            int row = lane >> 2;
            int prow = __shfl(pos, s * 16 + row, 64);
            bool rvalid = (base + s * 16 + row) < n;
#pragma unroll
            for (int pass = 0; pass < 2; pass++) {
                int chunk = (lane & 3) + 4 * pass;
                uint4 v = *(uint4*)&tst[row * 64 + chunk * 8];
                if (rvalid)
                    *(uint4*)&tsort[(size_t)prow * 64 + chunk * 8] = v;
            }
        }
    }
}

// ---------------------------------------------------------------------------
// Stage 2: aggregation (coalesced streaming over tsort) + output MLP.
// ---------------------------------------------------------------------------
__global__ __launch_bounds__(TPB) void agg_outmlp_kernel(
    const unsigned short* __restrict__ tsort,
    const int* __restrict__ off,
    const float* __restrict__ wo0, const float* __restrict__ bo0,
    const float* __restrict__ wo1, const float* __restrict__ bo1,
    float* __restrict__ out)
{
    __shared__ float s_agg[NCB * 64];    // 8 KB
    __shared__ float s_mid[NCB * 128];   // 16 KB
    int tid = threadIdx.x;
    int c0 = blockIdx.x * NCB;
    const unsigned int* t32 = (const unsigned int*)tsort;

    // phase A: aggregate
    {
        int l = tid & 63;
        int w = tid >> 6;
#define BF_LO(u) (__uint_as_float((u) << 16))
#define BF_HI(u) (__uint_as_float((u) & 0xffff0000u))
        for (int lc = w * 8; lc < w * 8 + 8; lc++) {
            int rb = off[c0 + lc];
            int re = off[c0 + lc + 1];
            float a0 = 0.f, a1 = 0.f;
            int r = rb;
            for (; r + 8 <= re; r += 8) {
                unsigned int u0 = t32[(size_t)(r + 0) * 32 + l];
                unsigned int u1 = t32[(size_t)(r + 2) * 32 + l];
                unsigned int u2 = t32[(size_t)(r + 4) * 32 + l];
                unsigned int u3 = t32[(size_t)(r + 6) * 32 + l];
                a0 += BF_LO(u0) + BF_LO(u1) + BF_LO(u2) + BF_LO(u3);
                a1 += BF_HI(u0) + BF_HI(u1) + BF_HI(u2) + BF_HI(u3);
            }
            for (; r + 2 <= re; r += 2) {
                unsigned int u = t32[(size_t)r * 32 + l];
                a0 += BF_LO(u);
                a1 += BF_HI(u);
            }
            if (r < re && l < 32) {
                unsigned int u = t32[(size_t)r * 32 + l];
                a0 += BF_LO(u);
                a1 += BF_HI(u);
            }
            float b0 = __shfl(a0, (l + 32) & 63, 64);
            float b1 = __shfl(a1, (l + 32) & 63, 64);
            if (l < 32) {
                float2 v;
                v.x = a0 + b0;
                v.y = a1 + b1;
                *(float2*)&s_agg[lc * 64 + 2 * l] = v;
            }
        }
#undef BF_LO
#undef BF_HI
    }
    __syncthreads();

    // phase B: mid[NCB][128] = relu(agg @ wo0 + bo0)
    {
        int j = tid & 127;
        int g = tid >> 7;
        float acc[16];
        float b = bo0[j];
#pragma unroll
        for (int c = 0; c < 16; c++) acc[c] = b;
        for (int k = 0; k < 64; k += 4) {
            float w0 = wo0[(k + 0) * 128 + j];
            float w1 = wo0[(k + 1) * 128 + j];
            float w2 = wo0[(k + 2) * 128 + j];
            float w3 = wo0[(k + 3) * 128 + j];
#pragma unroll
            for (int c = 0; c < 16; c++) {
                const float4 av = *(const float4*)&s_agg[(g * 16 + c) * 64 + k];
                acc[c] = fmaf(av.x, w0, acc[c]);
                acc[c] = fmaf(av.y, w1, acc[c]);
                acc[c] = fmaf(av.z, w2, acc[c]);
                acc[c] = fmaf(av.w, w3, acc[c]);
            }
        }
#pragma unroll
        for (int c = 0; c < 16; c++)
            s_mid[(g * 16 + c) * 128 + j] = fmaxf(acc[c], 0.f);
    }
    __syncthreads();

    // phase C: out[NCB][256] = relu(mid @ wo1 + bo1)
    {
        int mm = tid;
        float acc[NCB];
        float b = bo1[mm];
#pragma unroll
        for (int c = 0; c < NCB; c++) acc[c] = b;
        for (int j = 0; j < 128; j += 4) {
            float w0 = wo1[(j + 0) * 256 + mm];
            float w1 = wo1[(j + 1) * 256 + mm];
            float w2 = wo1[(j + 2) * 256 + mm];
            float w3 = wo1[(j + 3) * 256 + mm];
#pragma unroll
            for (int c = 0; c < NCB; c++) {
                const float4 mv = *(const float4*)&s_mid[c * 128 + j];
                acc[c] = fmaf(mv.x, w0, acc[c]);
                acc[c] = fmaf(mv.y, w1, acc[c]);
                acc[c] = fmaf(mv.z, w2, acc[c]);
                acc[c] = fmaf(mv.w, w3, acc[c]);
            }
        }
#pragma unroll
        for (int c = 0; c < NCB; c++)
            out[(size_t)(c0 + c) * 256 + mm] = fmaxf(acc[c], 0.f);
    }
}

extern "C" void kernel_launch(void* const* d_in, const int* in_sizes, int n_in,
                              void* d_out, int out_size, void* d_ws, size_t ws_size,
                              hipStream_t stream)
{
    const float* pf      = (const float*)d_in[0];
    const int*   labels  = (const int*)d_in[1];
    const float* centers = (const float*)d_in[2];
    const float* points  = (const float*)d_in[3];
    const float* we0 = (const float*)d_in[4];
    const float* be0 = (const float*)d_in[5];
    const float* we1 = (const float*)d_in[6];
    const float* be1 = (const float*)d_in[7];
    const float* we2 = (const float*)d_in[8];
    const float* be2 = (const float*)d_in[9];
    const float* we3 = (const float*)d_in[10];
    const float* be3 = (const float*)d_in[11];
    const float* wa0 = (const float*)d_in[12];
    const float* ba0 = (const float*)d_in[13];
    const float* wa1 = (const float*)d_in[14];
    const float* ba1 = (const float*)d_in[15];
    const float* wo0 = (const float*)d_in[16];
    const float* bo0 = (const float*)d_in[17];
    const float* wo1 = (const float*)d_in[18];
    const float* bo1 = (const float*)d_in[19];
    float* out = (float*)d_out;

    int n = in_sizes[0] / 8;        // N points (2,000,000)
    int C = in_sizes[2] / 3;        // clusters (65,536)

    // workspace layout
    int* counts = (int*)d_ws;                   // C
    int* cursor = counts + C;                   // C
    int* off    = cursor + C;                   // C+1
    uintptr_t tb = ((uintptr_t)(off + C + 1) + 255) & ~(uintptr_t)255;
    unsigned short* tsort = (unsigned short*)tb; // n x 64 bf16, cluster-sorted

    hipMemsetAsync(counts, 0, (size_t)C * sizeof(int), stream);

    int pblocks = (n + TPB - 1) / TPB;
    hist_kernel<<<pblocks, TPB, 0, stream>>>(labels, counts, n);
    scan_kernel<<<1, 1024, 0, stream>>>(counts, off, cursor, C);

    point_mlp_mfma<<<2048, TPB, 0, stream>>>(
        pf, labels, centers, points,
        we0, be0, we1, be1, we2, be2, we3, be3,
        wa0, ba0, wa1, ba1, cursor, tsort, n);

    agg_outmlp_kernel<<<C / NCB, TPB, 0, stream>>>(
        tsort, off, wo0, bo0, wo1, bo1, out);
}

// Round 6
// 625.443 us; speedup vs baseline: 1.2163x; 1.2163x over previous
//
#include <hip/hip_runtime.h>
#include <hip/hip_bf16.h>
#include <math.h>
#include <stdint.h>

#define TPB 256
#define NCB 32   // clusters per agg block

// ---------------------------------------------------------------------------
// Sort stage 1: histogram of labels
// ---------------------------------------------------------------------------
__global__ __launch_bounds__(TPB) void hist_kernel(
    const int* __restrict__ labels, int* __restrict__ counts, int n)
{
    int i = blockIdx.x * TPB + threadIdx.x;
    if (i < n) atomicAdd(&counts[labels[i]], 1);
}

// ---------------------------------------------------------------------------
// Parallel scan over C bins, 3 kernels (replaces the single-block scan that
// was ~HBM-latency-bound on one CU):
//   S1: per-256-bin block: local exclusive scan -> off, block total -> bsum
//   S2: one block scans bsum (<=256 blocks) -> exclusive bases; off[C]=n
//   S3: off[i] += base[block]; cursor[i] = off[i]
// ---------------------------------------------------------------------------
__global__ __launch_bounds__(256) void scan_local(
    const int* __restrict__ counts, int* __restrict__ off,
    int* __restrict__ bsum, int C)
{
    __shared__ int sh[256];
    int t = threadIdx.x;
    int i = blockIdx.x * 256 + t;
    int v = (i < C) ? counts[i] : 0;
    sh[t] = v;
    __syncthreads();
    for (int d = 1; d < 256; d <<= 1) {
        int u = (t >= d) ? sh[t - d] : 0;
        __syncthreads();
        sh[t] += u;
        __syncthreads();
    }
    if (i < C) off[i] = sh[t] - v;          // local exclusive prefix
    if (t == 255) bsum[blockIdx.x] = sh[255];
}

__global__ __launch_bounds__(256) void scan_base(
    int* __restrict__ bsum, int* __restrict__ off, int nb, int C)
{
    __shared__ int sh[256];
    int t = threadIdx.x;
    int v = (t < nb) ? bsum[t] : 0;
    sh[t] = v;
    __syncthreads();
    for (int d = 1; d < 256; d <<= 1) {
        int u = (t >= d) ? sh[t - d] : 0;
        __syncthreads();
        sh[t] += u;
        __syncthreads();
    }
    if (t < nb) bsum[t] = sh[t] - v;        // exclusive base per block
    if (t == 255) off[C] = sh[255];         // total == n
}

__global__ __launch_bounds__(256) void scan_apply(
    int* __restrict__ off, int* __restrict__ cursor,
    const int* __restrict__ bsum, int C)
{
    int i = blockIdx.x * 256 + threadIdx.x;
    if (i < C) {
        int v = off[i] + bsum[blockIdx.x];
        off[i] = v;
        cursor[i] = v;
    }
}

// ---------------------------------------------------------------------------
// Stage 1: per-point MLP (round-4 proven version: 1 point/thread, coalesced
// input reads, no LDS). Claims sorted slot via cursor atomic and writes the
// gated bf16 64-vector row at the sorted position (128B = 1 cacheline).
// ---------------------------------------------------------------------------
__global__ __launch_bounds__(TPB) void point_mlp_kernel(
    const float* __restrict__ pf, const int* __restrict__ labels,
    const float* __restrict__ centers, const float* __restrict__ points,
    const float* __restrict__ we0, const float* __restrict__ be0,
    const float* __restrict__ we1, const float* __restrict__ be1,
    const float* __restrict__ we2, const float* __restrict__ be2,
    const float* __restrict__ we3, const float* __restrict__ be3,
    const float* __restrict__ wa0, const float* __restrict__ ba0,
    const float* __restrict__ wa1, const float* __restrict__ ba1,
    int* __restrict__ cursor, unsigned short* __restrict__ tsort, int n)
{
    int i = blockIdx.x * TPB + threadIdx.x;
    if (i >= n) return;

    float x[11];
    const float4* pf4 = (const float4*)pf;
    float4 p0 = pf4[(size_t)i * 2 + 0];
    float4 p1 = pf4[(size_t)i * 2 + 1];
    x[0] = p0.x; x[1] = p0.y; x[2] = p0.z; x[3] = p0.w;
    x[4] = p1.x; x[5] = p1.y; x[6] = p1.z; x[7] = p1.w;

    int lbl = labels[i];
    x[8]  = centers[lbl * 3 + 0] - points[(size_t)i * 3 + 0];
    x[9]  = centers[lbl * 3 + 1] - points[(size_t)i * 3 + 1];
    x[10] = centers[lbl * 3 + 2] - points[(size_t)i * 3 + 2];

    // claim sorted slot early; latency overlaps the MLP compute below
    int pos = atomicAdd(&cursor[lbl], 1);

    // attention MLP: 11 -> 64 relu -> 1 sigmoid
    float s = ba1[0];
#pragma unroll
    for (int j = 0; j < 64; j++) {
        float aj = ba0[j];
#pragma unroll
        for (int k = 0; k < 11; k++) aj = fmaf(x[k], wa0[k * 64 + j], aj);
        aj = fmaxf(aj, 0.f);
        s = fmaf(aj, wa1[j], s);
    }
    float gate = 1.f / (1.f + __expf(-s));

    // edge MLP: 11 -> 8 -> 16 -> 32
    float h1[8];
#pragma unroll
    for (int j = 0; j < 8; j++) {
        float v = be0[j];
#pragma unroll
        for (int k = 0; k < 11; k++) v = fmaf(x[k], we0[k * 8 + j], v);
        h1[j] = fmaxf(v, 0.f);
    }
    float h2[16];
#pragma unroll
    for (int j = 0; j < 16; j++) {
        float v = be1[j];
#pragma unroll
        for (int k = 0; k < 8; k++) v = fmaf(h1[k], we1[k * 16 + j], v);
        h2[j] = fmaxf(v, 0.f);
    }
    float h3[32];
#pragma unroll
    for (int j = 0; j < 32; j++) {
        float v = be2[j];
#pragma unroll
        for (int k = 0; k < 16; k++) v = fmaf(h2[k], we2[k * 32 + j], v);
        h3[j] = fmaxf(v, 0.f);
    }

    // final layer 32 -> 64, relu, gate, pack bf16, store row at sorted pos
    uint4* dst = (uint4*)(tsort + (size_t)pos * 64);
#pragma unroll
    for (int g = 0; g < 8; g++) {
        unsigned int w[4];
#pragma unroll
        for (int q = 0; q < 4; q++) {
            unsigned int packed = 0;
#pragma unroll
            for (int h = 0; h < 2; h++) {
                int j = g * 8 + q * 2 + h;
                float v = be3[j];
#pragma unroll
                for (int k = 0; k < 32; k++) v = fmaf(h3[k], we3[k * 64 + j], v);
                v = fmaxf(v, 0.f) * gate;
                __hip_bfloat16 b = __float2bfloat16(v);
                unsigned short us = *(unsigned short*)&b;
                packed |= ((unsigned int)us) << (16 * h);
            }
            w[q] = packed;
        }
        dst[g] = make_uint4(w[0], w[1], w[2], w[3]);
    }
}

// ---------------------------------------------------------------------------
// Stage 2: aggregation (coalesced streaming over tsort) + output MLP.
// ---------------------------------------------------------------------------
__global__ __launch_bounds__(TPB) void agg_outmlp_kernel(
    const unsigned short* __restrict__ tsort,
    const int* __restrict__ off,
    const float* __restrict__ wo0, const float* __restrict__ bo0,
    const float* __restrict__ wo1, const float* __restrict__ bo1,
    float* __restrict__ out)
{
    __shared__ float s_agg[NCB * 64];    // 8 KB
    __shared__ float s_mid[NCB * 128];   // 16 KB
    int tid = threadIdx.x;
    int c0 = blockIdx.x * NCB;
    const unsigned int* t32 = (const unsigned int*)tsort;

    // phase A: aggregate
    {
        int l = tid & 63;
        int w = tid >> 6;
#define BF_LO(u) (__uint_as_float((u) << 16))
#define BF_HI(u) (__uint_as_float((u) & 0xffff0000u))
        for (int lc = w * 8; lc < w * 8 + 8; lc++) {
            int rb = off[c0 + lc];
            int re = off[c0 + lc + 1];
            float a0 = 0.f, a1 = 0.f;
            int r = rb;
            for (; r + 8 <= re; r += 8) {
                unsigned int u0 = t32[(size_t)(r + 0) * 32 + l];
                unsigned int u1 = t32[(size_t)(r + 2) * 32 + l];
                unsigned int u2 = t32[(size_t)(r + 4) * 32 + l];
                unsigned int u3 = t32[(size_t)(r + 6) * 32 + l];
                a0 += BF_LO(u0) + BF_LO(u1) + BF_LO(u2) + BF_LO(u3);
                a1 += BF_HI(u0) + BF_HI(u1) + BF_HI(u2) + BF_HI(u3);
            }
            for (; r + 2 <= re; r += 2) {
                unsigned int u = t32[(size_t)r * 32 + l];
                a0 += BF_LO(u);
                a1 += BF_HI(u);
            }
            if (r < re && l < 32) {
                unsigned int u = t32[(size_t)r * 32 + l];
                a0 += BF_LO(u);
                a1 += BF_HI(u);
            }
            float b0 = __shfl(a0, (l + 32) & 63, 64);
            float b1 = __shfl(a1, (l + 32) & 63, 64);
            if (l < 32) {
                float2 v;
                v.x = a0 + b0;
                v.y = a1 + b1;
                *(float2*)&s_agg[lc * 64 + 2 * l] = v;
            }
        }
#undef BF_LO
#undef BF_HI
    }
    __syncthreads();

    // phase B: mid[NCB][128] = relu(agg @ wo0 + bo0)
    {
        int j = tid & 127;
        int g = tid >> 7;
        float acc[16];
        float b = bo0[j];
#pragma unroll
        for (int c = 0; c < 16; c++) acc[c] = b;
        for (int k = 0; k < 64; k += 4) {
            float w0 = wo0[(k + 0) * 128 + j];
            float w1 = wo0[(k + 1) * 128 + j];
            float w2 = wo0[(k + 2) * 128 + j];
            float w3 = wo0[(k + 3) * 128 + j];
#pragma unroll
            for (int c = 0; c < 16; c++) {
                const float4 av = *(const float4*)&s_agg[(g * 16 + c) * 64 + k];
                acc[c] = fmaf(av.x, w0, acc[c]);
                acc[c] = fmaf(av.y, w1, acc[c]);
                acc[c] = fmaf(av.z, w2, acc[c]);
                acc[c] = fmaf(av.w, w3, acc[c]);
            }
        }
#pragma unroll
        for (int c = 0; c < 16; c++)
            s_mid[(g * 16 + c) * 128 + j] = fmaxf(acc[c], 0.f);
    }
    __syncthreads();

    // phase C: out[NCB][256] = relu(mid @ wo1 + bo1)
    {
        int m = tid;
        float acc[NCB];
        float b = bo1[m];
#pragma unroll
        for (int c = 0; c < NCB; c++) acc[c] = b;
        for (int j = 0; j < 128; j += 4) {
            float w0 = wo1[(j + 0) * 256 + m];
            float w1 = wo1[(j + 1) * 256 + m];
            float w2 = wo1[(j + 2) * 256 + m];
            float w3 = wo1[(j + 3) * 256 + m];
#pragma unroll
            for (int c = 0; c < NCB; c++) {
                const float4 mv = *(const float4*)&s_mid[c * 128 + j];
                acc[c] = fmaf(mv.x, w0, acc[c]);
                acc[c] = fmaf(mv.y, w1, acc[c]);
                acc[c] = fmaf(mv.z, w2, acc[c]);
                acc[c] = fmaf(mv.w, w3, acc[c]);
            }
        }
#pragma unroll
        for (int c = 0; c < NCB; c++)
            out[(size_t)(c0 + c) * 256 + m] = fmaxf(acc[c], 0.f);
    }
}

extern "C" void kernel_launch(void* const* d_in, const int* in_sizes, int n_in,
                              void* d_out, int out_size, void* d_ws, size_t ws_size,
                              hipStream_t stream)
{
    const float* pf      = (const float*)d_in[0];
    const int*   labels  = (const int*)d_in[1];
    const float* centers = (const float*)d_in[2];
    const float* points  = (const float*)d_in[3];
    const float* we0 = (const float*)d_in[4];
    const float* be0 = (const float*)d_in[5];
    const float* we1 = (const float*)d_in[6];
    const float* be1 = (const float*)d_in[7];
    const float* we2 = (const float*)d_in[8];
    const float* be2 = (const float*)d_in[9];
    const float* we3 = (const float*)d_in[10];
    const float* be3 = (const float*)d_in[11];
    const float* wa0 = (const float*)d_in[12];
    const float* ba0 = (const float*)d_in[13];
    const float* wa1 = (const float*)d_in[14];
    const float* ba1 = (const float*)d_in[15];
    const float* wo0 = (const float*)d_in[16];
    const float* bo0 = (const float*)d_in[17];
    const float* wo1 = (const float*)d_in[18];
    const float* bo1 = (const float*)d_in[19];
    float* out = (float*)d_out;

    int n = in_sizes[0] / 8;        // N points (2,000,000)
    int C = in_sizes[2] / 3;        // clusters (65,536)

    // workspace layout
    int* counts = (int*)d_ws;                   // C
    int* cursor = counts + C;                   // C
    int* off    = cursor + C;                   // C+1
    int* bsum   = off + C + 1;                  // <=256
    uintptr_t tb = ((uintptr_t)(bsum + 256) + 255) & ~(uintptr_t)255;
    unsigned short* tsort = (unsigned short*)tb; // n x 64 bf16, cluster-sorted

    hipMemsetAsync(counts, 0, (size_t)C * sizeof(int), stream);

    int pblocks = (n + TPB - 1) / TPB;
    int nb = (C + 255) / 256;                   // 256 scan blocks
    hist_kernel<<<pblocks, TPB, 0, stream>>>(labels, counts, n);
    scan_local<<<nb, 256, 0, stream>>>(counts, off, bsum, C);
    scan_base<<<1, 256, 0, stream>>>(bsum, off, nb, C);
    scan_apply<<<nb, 256, 0, stream>>>(off, cursor, bsum, C);

    point_mlp_kernel<<<pblocks, TPB, 0, stream>>>(
        pf, labels, centers, points,
        we0, be0, we1, be1, we2, be2, we3, be3,
        wa0, ba0, wa1, ba1, cursor, tsort, n);

    agg_outmlp_kernel<<<C / NCB, TPB, 0, stream>>>(
        tsort, off, wo0, bo0, wo1, bo1, out);
}